// Round 8
// baseline (217.200 us; speedup 1.0000x reference)
//
#include <hip/hip_runtime.h>
#include <math.h>

// Shapes (fixed): B=32, M=2, C=256, H=W=16, N=256, DIM=256, THR=0.1, RATIO=0.8
// out: fused (32,256,16,16) = 2,097,152 floats, then auto_enc_loss (1 float)
//
// R8: conv GEMM core now uses k-split wave tiling: 8 waves = 2x2 wave grid x
// ksplit2, each wave 64x64 out x 32k per kit -> 8 ds_read_b128 per 16 MFMA
// (was 12): LDS-read-BW (the measured binding pipe) cut 33%. One-time
// cross-ksplit LDS reduction in epilogue. conv_enc + recgemm merged into one
// 384-block dispatch. 6 launches.

typedef __attribute__((ext_vector_type(8))) short short8;
typedef __attribute__((ext_vector_type(4))) float f32x4;

__device__ __forceinline__ void gload_lds16(const void* g, void* l) {
  __builtin_amdgcn_global_load_lds(
      (const __attribute__((address_space(1))) void*)g,
      (__attribute__((address_space(3))) void*)l, 16, 0, 0);
}

__device__ __forceinline__ unsigned short f2bf(float f) {
  unsigned u = __float_as_uint(f);
  unsigned r = (u + 0x7FFFu + ((u >> 16) & 1u)) >> 16;  // RNE
  return (unsigned short)r;
}

__device__ __forceinline__ unsigned mapf(float f) {
  unsigned u = __float_as_uint(f);
  return (u & 0x80000000u) ? ~u : (u | 0x80000000u);   // monotone float->uint
}
__device__ __forceinline__ float unmapf(unsigned u) {
  unsigned v = (u & 0x80000000u) ? (u & 0x7fffffffu) : ~u;
  return __uint_as_float(v);
}

// ---------------- merged prep: pack | weight-repack | halo-zero | slots | init
__global__ __launch_bounds__(256) void prep_k(
    const float* __restrict__ cf, const float* __restrict__ we,
    const float* __restrict__ wd, const float* __restrict__ fv,
    unsigned short* __restrict__ Xp, unsigned short* __restrict__ WrE,
    unsigned short* __restrict__ WrD, int* __restrict__ smr,
    float* __restrict__ vd, float4* __restrict__ sraw4,
    float* __restrict__ lacc, unsigned* __restrict__ mm) {
  const int bx = blockIdx.x, t = threadIdx.x;
  if (bx < 2048) {                       // pack: cf NCHW f32 -> padded NHWC bf16
    int idx = bx * 256 + t;
    int p = idx & 255, ch = (idx >> 8) & 31, img = idx >> 13;  // lanes ~ p: coalesced
    int ic0 = ch * 8;
    const float* sp = cf + (size_t)img * 65536 + (size_t)ic0 * 256 + p;
    unsigned short h[8];
#pragma unroll
    for (int i = 0; i < 8; ++i) h[i] = f2bf(sp[i * 256]);
    int y = p >> 4, x = p & 15;
    uint4 u;
    u.x = h[0] | (h[1] << 16); u.y = h[2] | (h[3] << 16);
    u.z = h[4] | (h[5] << 16); u.w = h[6] | (h[7] << 16);
    *(uint4*)&Xp[(size_t)img * 82944 + (size_t)(y * 18 + x + 19) * 256 + ic0] = u;
  } else if (bx < 2624) {                // wrk: OIHW f32 -> Wr[oc][s][ic] bf16
    int idx = (bx - 2048) * 256 + t;
    int ch = idx & 31, rest = idx >> 5;
    int s = rest % 9, ocx = rest / 9;
    int oc = ocx & 255, cv = ocx >> 8;
    const float* w = cv ? wd : we;
    unsigned short* o = cv ? WrD : WrE;
    int ic0 = ch * 8;
    unsigned short h[8];
#pragma unroll
    for (int i = 0; i < 8; ++i) h[i] = f2bf(w[(size_t)oc * 2304 + (ic0 + i) * 9 + s]);
    uint4 u;
    u.x = h[0] | (h[1] << 16); u.y = h[2] | (h[3] << 16);
    u.z = h[4] | (h[5] << 16); u.w = h[6] | (h[7] << 16);
    *(uint4*)&o[(size_t)oc * 2304 + s * 256 + ic0] = u;
  } else if (bx < 2752) {                // halo zero: Xp imgs 0..63, Midp 64..127
    int img = bx - 2624;
    uint4* base = (uint4*)Xp + (size_t)img * 10368;
    uint4 z; z.x = z.y = z.z = z.w = 0;
    for (int it = t; it < 2176; it += 256) {
      int px = it >> 5, c = it & 31;
      int y, x;
      if (px < 18)      { y = 0;  x = px; }
      else if (px < 36) { y = 17; x = px - 18; }
      else if (px < 52) { y = px - 35; x = 0; }
      else              { y = px - 51; x = 17; }
      base[(y * 18 + x) * 32 + c] = z;
    }
  } else if (bx < 2784) {                // slots: rank budget + dest maps
    const int b = bx - 2752;
    const float v0 = fv[(size_t)b * 512 + t];
    const float v1 = fv[(size_t)b * 512 + 256 + t];
    const unsigned long long bal0 = __ballot(v0 > 0.1f);
    const unsigned long long bal1 = __ballot(v1 > 0.1f);
    __shared__ int cnt0[4], cnt1[4], fc[2];
    const int wid = t >> 6, lane = t & 63;
    if (lane == 0) { cnt0[wid] = __popcll(bal0); cnt1[wid] = __popcll(bal1); }
    smr[b * 256 + t] = -1;
    vd[b * 256 + t] = 0.f;
    __syncthreads();
    if (t == 0) {
      int c0 = cnt0[0] + cnt0[1] + cnt0[2] + cnt0[3];
      int c1 = cnt1[0] + cnt1[1] + cnt1[2] + cnt1[3];
      int total = c0 + c1;
      int f0, f1;
      if (total > 256) {
        int a0 = (int)rintf(256.0f * (float)c0 / (float)total);
        f0 = a0; f1 = 256 - a0;
      } else { f0 = c0; f1 = c1; }
      fc[0] = max(f0, 0); fc[1] = max(f1, 0);
    }
    __syncthreads();
    const int c0 = fc[0], c1 = fc[1];
    if (t < c0) { smr[b * 256 + t] = t; vd[b * 256 + t] = v0; }
    if (t < c1) {
      int d = c0 + t;
      if (d < 256) { smr[b * 256 + d] = 256 + t; vd[b * 256 + d] = v1; }
    }
  } else {                               // zero sraw (24 blocks) + init (1)
    int z = bx - 2784;
    if (z < 24) {
      float4 zz; zz.x = zz.y = zz.z = zz.w = 0.f;
      sraw4[z * 256 + t] = zz;
    } else if (t == 0) {
      lacc[0] = 0.f; mm[0] = 0xFFFFFFFFu; mm[1] = 0u;
    }
  }
}

// ---------------- merged: ansb [0,1024) | bmt-transpose [1024,1152) | Recp halo [1152,1184)
__global__ __launch_bounds__(256) void ansbmt_k(
    const float* __restrict__ fs, const float* __restrict__ fd,
    const int* __restrict__ smr, const float* __restrict__ vd,
    unsigned short* __restrict__ Ans, unsigned short* __restrict__ BmT,
    unsigned short* __restrict__ Recp) {
  const int bx = blockIdx.x, t = threadIdx.x;
  if (bx < 1024) {                       // Ans[b][c][j] = ns[c][j]*v_j
    int idx = bx * 256 + t;
    int ch = idx & 31, c = (idx >> 5) & 255, b = idx >> 13;
    int j0 = ch * 8;
    int si = smr[b * 256 + c];
    unsigned short h[8] = {0, 0, 0, 0, 0, 0, 0, 0};
    if (si >= 0) {
      int m = si >> 8, r = si & 255;
      const float* fp = fs + (((size_t)b * 2 + m) * 256 + r) * 256 + j0;
      const float* vp = vd + b * 256 + j0;
#pragma unroll
      for (int i = 0; i < 8; ++i) h[i] = f2bf(fp[i] * vp[i]);
    }
    uint4 u;
    u.x = h[0] | (h[1] << 16); u.y = h[2] | (h[3] << 16);
    u.z = h[4] | (h[5] << 16); u.w = h[6] | (h[7] << 16);
    *(uint4*)&Ans[(size_t)b * 65536 + c * 256 + j0] = u;
  } else if (bx < 1152) {                // BmT[b][p][j] = fd[b,m_p,j,r_p]
    __shared__ float sIn[4096];          // 8 j x 2 m x 256 r
    const int b = (bx - 1024) >> 2, bz = (bx - 1024) & 3;
    const int sp = smr[b * 256 + t];
    const int m_p = sp >> 8, r_p = sp & 255;
    for (int jg = bz * 8; jg < bz * 8 + 8; ++jg) {
      __syncthreads();
#pragma unroll
      for (int u = 0; u < 4; ++u) {
        int q = t * 4 + u;
        int rr = q >> 6, w = q & 63;
        int m = rr >> 3, i = rr & 7;
        float4 f = ((const float4*)fd)[((size_t)(b * 2 + m) * 256 + jg * 8 + i) * 64 + w];
        *(float4*)&sIn[i * 512 + m * 256 + w * 4] = f;
      }
      __syncthreads();
      unsigned short h[8] = {0, 0, 0, 0, 0, 0, 0, 0};
      if (sp >= 0) {
#pragma unroll
        for (int i = 0; i < 8; ++i) h[i] = f2bf(sIn[i * 512 + m_p * 256 + r_p]);
      }
      uint4 u;
      u.x = h[0] | (h[1] << 16); u.y = h[2] | (h[3] << 16);
      u.z = h[4] | (h[5] << 16); u.w = h[6] | (h[7] << 16);
      *(uint4*)&BmT[(size_t)b * 65536 + t * 256 + jg * 8] = u;
    }
  } else {                               // Recp halo zero (32 imgs)
    int img = bx - 1152;
    uint4* base = (uint4*)Recp + (size_t)img * 10368;
    uint4 z; z.x = z.y = z.z = z.w = 0;
    for (int it = t; it < 2176; it += 256) {
      int px = it >> 5, c = it & 31;
      int y, x;
      if (px < 18)      { y = 0;  x = px; }
      else if (px < 36) { y = 17; x = px - 18; }
      else if (px < 52) { y = px - 35; x = 0; }
      else              { y = px - 51; x = 17; }
      base[(y * 18 + x) * 32 + c] = z;
    }
  }
}

// ======= GEMM core (shared by encrec/dec): 128x128 tile, BK=64, 512 thr.
// LDS buf 32KB (A [0,16K), B [16K,32K)), 2-deep. Wave layout: ksplit=wave>>2
// picks 32-k half; wq=wave&3 -> 2x2 grid of 64x64 out. 8 reads -> 16 MFMA.

// encrec: blocks [0,256) = enc conv (Xp*WrE -> relu -> Midp);
//         blocks [256,384) = recgemm (BmT x Ans -> Recp), 4 kits.
__global__ __launch_bounds__(512, 4) void encrec_k(
    const unsigned short* __restrict__ Xin, const unsigned short* __restrict__ Wr,
    const float* __restrict__ bias, unsigned short* __restrict__ Midp,
    const unsigned short* __restrict__ BmT, const unsigned short* __restrict__ Ans,
    unsigned short* __restrict__ Recp) {
  __shared__ __align__(16) char S[65536];
  const int t = threadIdx.x, lane = t & 63, wave = t >> 6;
  const int ksplit = wave >> 2, wq = wave & 3;
  const int mw = wq >> 1, nw = wq & 1;
  const int mlane = lane & 15, quad = lane >> 4;
  const int L = blockIdx.x;
  const bool isConv = L < 256;

  int img = 0, b = 0, pt, ot, nkits;
  const char *Ag, *Bg;
  int laneA[2], laneB[2];
  if (isConv) {
    int xcd = L & 7, sl = L >> 3;
    img = xcd * 8 + (sl & 7);
    int tile = sl >> 3;
    pt = tile >> 1; ot = tile & 1;
    Ag = (const char*)Xin + (size_t)img * 165888;
    Bg = (const char*)Wr;
#pragma unroll
    for (int r = 0; r < 2; ++r) {
      int id = r * 512 + t;
      int row = id >> 3, sub = id & 7, q = sub ^ (row & 7);
      int p = pt * 128 + row, y = p >> 4, x = p & 15;
      laneA[r] = (y * 18 + x) * 512 + q * 16;
      laneB[r] = (ot * 128 + row) * 4608 + q * 16;
    }
    nkits = 36;
  } else {
    int l2 = L - 256;
    b = l2 >> 2;
    int tile = l2 & 3;
    pt = tile >> 1; ot = tile & 1;
    Ag = (const char*)BmT + (size_t)b * 131072;
    Bg = (const char*)Ans + (size_t)b * 131072;
#pragma unroll
    for (int r = 0; r < 2; ++r) {
      int id = r * 512 + t;
      int row = id >> 3, sub = id & 7, q = sub ^ (row & 7);
      laneA[r] = (pt * 128 + row) * 512 + q * 16;
      laneB[r] = (ot * 128 + row) * 512 + q * 16;
    }
    nkits = 4;
  }

  int aoff[4], boff[4];
#pragma unroll
  for (int i = 0; i < 4; ++i) {
    int rowm = mw * 64 + i * 16 + mlane;
    aoff[i] = rowm * 128 + (((ksplit * 4 + quad) ^ (rowm & 7)) * 16);
    int rown = nw * 64 + i * 16 + mlane;
    boff[i] = 16384 + rown * 128 + (((ksplit * 4 + quad) ^ (rown & 7)) * 16);
  }

  auto stage = [&](int kit, int buf) {
    int aG, bG = kit * 128;
    if (isConv) {
      int s = kit >> 2;
      int dy = s / 3, dx = s - dy * 3;
      aG = (dy * 18 + dx) * 512 + (kit & 3) * 128;
    } else {
      aG = kit * 128;
    }
    char* dst = S + buf * 32768;
#pragma unroll
    for (int r = 0; r < 2; ++r)
      gload_lds16(Ag + laneA[r] + aG, dst + r * 8192 + wave * 1024);
#pragma unroll
    for (int r = 0; r < 2; ++r)
      gload_lds16(Bg + laneB[r] + bG, dst + 16384 + r * 8192 + wave * 1024);
  };

  f32x4 acc[4][4] = {};
  for (int preload = 0; preload < 1; ++preload) stage(0, 0);
  for (int kit = 0; kit < nkits; ++kit) {
    int cur = kit & 1;
    asm volatile("s_waitcnt vmcnt(0)" ::: "memory");
    asm volatile("s_barrier" ::: "memory");
    if (kit + 1 < nkits) stage(kit + 1, 1 - cur);
    const char* Sb = S + cur * 32768;
    short8 af[4], bf[4];
#pragma unroll
    for (int i = 0; i < 4; ++i) {
      af[i] = *(const short8*)(Sb + aoff[i]);
      bf[i] = *(const short8*)(Sb + boff[i]);
    }
#pragma unroll
    for (int i = 0; i < 4; ++i)
#pragma unroll
      for (int n = 0; n < 4; ++n)
        acc[i][n] = __builtin_amdgcn_mfma_f32_16x16x32_bf16(af[i], bf[n], acc[i][n], 0, 0, 0);
  }

  // cross-ksplit reduction through LDS
  __syncthreads();
  if (ksplit == 1) {
#pragma unroll
    for (int i = 0; i < 4; ++i)
#pragma unroll
      for (int n = 0; n < 4; ++n)
        *(f32x4*)(S + wq * 16384 + (i * 4 + n) * 1024 + lane * 16) = acc[i][n];
  }
  __syncthreads();
  if (ksplit == 0) {
#pragma unroll
    for (int i = 0; i < 4; ++i)
#pragma unroll
      for (int n = 0; n < 4; ++n)
        acc[i][n] += *(const f32x4*)(S + wq * 16384 + (i * 4 + n) * 1024 + lane * 16);
    if (isConv) {
#pragma unroll
      for (int i = 0; i < 4; ++i) {
        int m0 = pt * 128 + mw * 64 + i * 16 + quad * 4;
#pragma unroll
        for (int n = 0; n < 4; ++n) {
          int oc = ot * 128 + nw * 64 + n * 16 + mlane;
          float bv = bias[oc];
#pragma unroll
          for (int r = 0; r < 4; ++r) {
            int p = m0 + r;
            int y = p >> 4, x = p & 15;
            float v = fmaxf(acc[i][n][r] + bv, 0.f);
            Midp[(size_t)img * 82944 + (size_t)(y * 18 + x + 19) * 256 + oc] = f2bf(v);
          }
        }
      }
    } else {
#pragma unroll
      for (int i = 0; i < 4; ++i) {
        int m0 = pt * 128 + mw * 64 + i * 16 + quad * 4;
#pragma unroll
        for (int n = 0; n < 4; ++n) {
          int cc = ot * 128 + nw * 64 + n * 16 + mlane;
#pragma unroll
          for (int r = 0; r < 4; ++r) {
            int p = m0 + r;
            int y = p >> 4, x = p & 15;
            Recp[(size_t)b * 82944 + (size_t)(y * 18 + x + 19) * 256 + cc] = f2bf(acc[i][n][r]);
          }
        }
      }
    }
  }
}

// dec merged: units 0..63 = dec(Midp)+loss vs cf; units 64..95 = dec(Recp)->rec2+minmax
__global__ __launch_bounds__(512, 4) void conv_dec_k(
    const unsigned short* __restrict__ Midp, const unsigned short* __restrict__ Recp,
    const unsigned short* __restrict__ Wr, const float* __restrict__ bias,
    const float* __restrict__ cfref, float* __restrict__ rec2,
    float* __restrict__ lacc, unsigned* __restrict__ mm) {
  __shared__ __align__(16) char S[65536];
  __shared__ float sred[4], smn[4], smx[4];
  const int t = threadIdx.x, lane = t & 63, wave = t >> 6;
  const int ksplit = wave >> 2, wq = wave & 3;
  const int mw = wq >> 1, nw = wq & 1;
  const int mlane = lane & 15, quad = lane >> 4;
  const int L = blockIdx.x;
  const int xcd = L & 7, sl = L >> 3;          // 384 blocks: sl 0..47
  const int u12 = sl % 12, tile = sl / 12;     // tile 0..3
  const int unit = xcd * 12 + u12;             // 0..95
  const bool isLoss = unit < 64;
  const int pt = tile >> 1, ot = tile & 1;

  int laneA[2], laneB[2];
#pragma unroll
  for (int r = 0; r < 2; ++r) {
    int id = r * 512 + t;
    int row = id >> 3, sub = id & 7, q = sub ^ (row & 7);
    int p = pt * 128 + row, y = p >> 4, x = p & 15;
    laneA[r] = (y * 18 + x) * 512 + q * 16;
    laneB[r] = (ot * 128 + row) * 4608 + q * 16;
  }
  const char* Ag = isLoss ? (const char*)Midp + (size_t)unit * 165888
                          : (const char*)Recp + (size_t)(unit - 64) * 165888;
  const char* Bg = (const char*)Wr;

  int aoff[4], boff[4];
#pragma unroll
  for (int i = 0; i < 4; ++i) {
    int rowm = mw * 64 + i * 16 + mlane;
    aoff[i] = rowm * 128 + (((ksplit * 4 + quad) ^ (rowm & 7)) * 16);
    int rown = nw * 64 + i * 16 + mlane;
    boff[i] = 16384 + rown * 128 + (((ksplit * 4 + quad) ^ (rown & 7)) * 16);
  }

  auto stage = [&](int kit, int buf) {
    int s = kit >> 2;
    int dy = s / 3, dx = s - dy * 3;
    int aG = (dy * 18 + dx) * 512 + (kit & 3) * 128;
    int bG = kit * 128;
    char* dst = S + buf * 32768;
#pragma unroll
    for (int r = 0; r < 2; ++r)
      gload_lds16(Ag + laneA[r] + aG, dst + r * 8192 + wave * 1024);
#pragma unroll
    for (int r = 0; r < 2; ++r)
      gload_lds16(Bg + laneB[r] + bG, dst + 16384 + r * 8192 + wave * 1024);
  };

  f32x4 acc[4][4] = {};
  stage(0, 0);
  for (int kit = 0; kit < 36; ++kit) {
    int cur = kit & 1;
    asm volatile("s_waitcnt vmcnt(0)" ::: "memory");
    asm volatile("s_barrier" ::: "memory");
    if (kit + 1 < 36) stage(kit + 1, 1 - cur);
    const char* Sb = S + cur * 32768;
    short8 af[4], bf[4];
#pragma unroll
    for (int i = 0; i < 4; ++i) {
      af[i] = *(const short8*)(Sb + aoff[i]);
      bf[i] = *(const short8*)(Sb + boff[i]);
    }
#pragma unroll
    for (int i = 0; i < 4; ++i)
#pragma unroll
      for (int n = 0; n < 4; ++n)
        acc[i][n] = __builtin_amdgcn_mfma_f32_16x16x32_bf16(af[i], bf[n], acc[i][n], 0, 0, 0);
  }

  __syncthreads();
  if (ksplit == 1) {
#pragma unroll
    for (int i = 0; i < 4; ++i)
#pragma unroll
      for (int n = 0; n < 4; ++n)
        *(f32x4*)(S + wq * 16384 + (i * 4 + n) * 1024 + lane * 16) = acc[i][n];
  }
  __syncthreads();
  if (ksplit == 0) {
#pragma unroll
    for (int i = 0; i < 4; ++i)
#pragma unroll
      for (int n = 0; n < 4; ++n)
        acc[i][n] += *(const f32x4*)(S + wq * 16384 + (i * 4 + n) * 1024 + lane * 16);

    if (isLoss) {
      float ls = 0.f;
#pragma unroll
      for (int i = 0; i < 4; ++i) {
        int m0 = pt * 128 + mw * 64 + i * 16 + quad * 4;
#pragma unroll
        for (int n = 0; n < 4; ++n) {
          int oc = ot * 128 + nw * 64 + n * 16 + mlane;
          float bv = bias[oc];
          float4 c4 = *(const float4*)(cfref + (size_t)unit * 65536 + (size_t)oc * 256 + m0);
          float d0 = acc[i][n][0] + bv - c4.x;
          float d1 = acc[i][n][1] + bv - c4.y;
          float d2 = acc[i][n][2] + bv - c4.z;
          float d3 = acc[i][n][3] + bv - c4.w;
          ls += d0 * d0 + d1 * d1 + d2 * d2 + d3 * d3;
        }
      }
#pragma unroll
      for (int off = 32; off; off >>= 1) ls += __shfl_down(ls, off);
      if (lane == 0) sred[wq] = ls;
    } else {
      const int img2 = unit - 64;
      float mn = INFINITY, mx = -INFINITY;
#pragma unroll
      for (int i = 0; i < 4; ++i) {
        int m0 = pt * 128 + mw * 64 + i * 16 + quad * 4;
#pragma unroll
        for (int n = 0; n < 4; ++n) {
          int oc = ot * 128 + nw * 64 + n * 16 + mlane;
          float bv = bias[oc];
          float4 v;
          v.x = acc[i][n][0] + bv; v.y = acc[i][n][1] + bv;
          v.z = acc[i][n][2] + bv; v.w = acc[i][n][3] + bv;
          mn = fminf(mn, fminf(fminf(v.x, v.y), fminf(v.z, v.w)));
          mx = fmaxf(mx, fmaxf(fmaxf(v.x, v.y), fmaxf(v.z, v.w)));
          *(float4*)(rec2 + (size_t)img2 * 65536 + (size_t)oc * 256 + m0) = v;
        }
      }
#pragma unroll
      for (int off = 32; off; off >>= 1) {
        mn = fminf(mn, __shfl_down(mn, off));
        mx = fmaxf(mx, __shfl_down(mx, off));
      }
      if (lane == 0) { smn[wq] = mn; smx[wq] = mx; }
    }
  }
  __syncthreads();
  if (t == 0) {
    if (isLoss) {
      atomicAdd(lacc, sred[0] + sred[1] + sred[2] + sred[3]);
    } else {
      float a = fminf(fminf(smn[0], smn[1]), fminf(smn[2], smn[3]));
      float b2 = fmaxf(fmaxf(smx[0], smx[1]), fmaxf(smx[2], smx[3]));
      atomicMin(&mm[0], mapf(a));
      atomicMax(&mm[1], mapf(b2));
    }
  }
}

// 256->1 score conv partials, ic-split 8-way, atomicAdd into sraw (pre-zeroed)
__global__ __launch_bounds__(256) void score_conv_k(
    const float* __restrict__ rec2, const float* __restrict__ cf,
    const float* __restrict__ wval, const unsigned* __restrict__ mm,
    float* __restrict__ sraw) {
  const int b = blockIdx.x, phase = blockIdx.y, icc = blockIdx.z;
  const int t = threadIdx.x;
  const int row = t >> 4, col = t & 15;
  __shared__ float s_in[8 * 360];
  __shared__ float s_wv[72];
  for (int i = t; i < 8 * 360; i += 256) s_in[i] = 0.f;
  const float* src;
  float sc = 1.f, sh = 0.f;
  int wofs;
  if (phase == 0) {
    src = rec2 + (size_t)b * 65536;
    float mn = unmapf(mm[0]), mx = unmapf(mm[1]);
    sc = 2.f / (mx - mn);
    sh = -mn * sc - 1.f;
    wofs = 0;
  } else {
    src = cf + ((size_t)b * 2 + (phase - 1)) * 65536;
    wofs = 2304;
  }
  float acc = 0.f;
  for (int ic0 = icc * 32; ic0 < icc * 32 + 32; ic0 += 8) {
    __syncthreads();
#pragma unroll
    for (int i = 0; i < 8; ++i) {
      float v = src[(ic0 + i) * 256 + t];
      if (phase == 0) v = fmaf(v, sc, sh);
      s_in[i * 360 + (row + 1) * 20 + (col + 1)] = v;
    }
    if (t < 72) s_wv[t] = wval[wofs + ic0 * 9 + t];
    __syncthreads();
#pragma unroll
    for (int i = 0; i < 8; ++i)
#pragma unroll
      for (int ky = 0; ky < 3; ++ky)
#pragma unroll
        for (int kx = 0; kx < 3; ++kx)
          acc += s_in[i * 360 + (row + ky) * 20 + (col + kx)] * s_wv[i * 9 + ky * 3 + kx];
  }
  atomicAdd(&sraw[((size_t)b * 3 + phase) * 256 + t], acc);
}

__global__ void fuse_k(const float* __restrict__ cf, const float* __restrict__ rec2,
                       const float* __restrict__ sraw, const float* __restrict__ bval,
                       const unsigned* __restrict__ mm, const float* __restrict__ lacc,
                       float* __restrict__ outp) {
  const int idx = blockIdx.x * 256 + threadIdx.x;
  const int b = idx >> 16;
  const int rest = idx & 65535;
  const int pos = idx & 255;
  const float mn = unmapf(mm[0]), mx = unmapf(mm[1]);
  const float sc = 2.f / (mx - mn), sh = -mn * sc - 1.f;
  const float srec = sraw[(size_t)b * 768 + pos];
  const float sc0 = sraw[(size_t)b * 768 + 256 + pos];
  const float sc1 = sraw[(size_t)b * 768 + 512 + pos];
  const float bv = bval[0];
  const float z0 = fmaxf(srec + sc0 + bv, 0.f);
  const float z1 = fmaxf(srec + sc1 + bv, 0.f);
  const float s0 = 1.f / (1.f + expf(-z0));
  const float s1 = 1.f / (1.f + expf(-z1));
  const float w0 = 1.f / (1.f + expf(s1 - s0));  // softmax over 2 modalities
  const float w1 = 1.f - w0;
  const float rn = fmaf(rec2[idx], sc, sh);
  const float f0 = cf[(size_t)b * 131072 + rest];
  const float f1 = cf[(size_t)b * 131072 + 65536 + rest];
  outp[idx] = 0.2f * (w0 * f0 + w1 * f1) + 0.8f * rn;
  if (idx == 0) outp[2097152] = lacc[0] * (1.f / 4194304.f);
}

extern "C" void kernel_launch(void* const* d_in, const int* in_sizes, int n_in,
                              void* d_out, int out_size, void* d_ws, size_t ws_size,
                              hipStream_t stream) {
  const float* cf    = (const float*)d_in[0];
  const float* fs    = (const float*)d_in[1];
  const float* fv    = (const float*)d_in[2];
  const float* fd    = (const float*)d_in[3];
  const float* w_enc = (const float*)d_in[4];
  const float* b_enc = (const float*)d_in[5];
  const float* w_dec = (const float*)d_in[6];
  const float* b_dec = (const float*)d_in[7];
  const float* w_val = (const float*)d_in[8];
  const float* b_val = (const float*)d_in[9];
  float* out = (float*)d_out;
  float* wsf = (float*)d_ws;

  // ws layout (float offsets) — no aliasing:
  unsigned short* Xp   = (unsigned short*)wsf;                  // 64 img padded NHWC
  unsigned short* Midp = (unsigned short*)(wsf + 2654208);      // 64 img (halo: prep imgs 64..127)
  unsigned short* Recp = (unsigned short*)(wsf + 5308416);      // 32 img
  float* rec2 = wsf + 6635520;                                  // 2,097,152 NCHW f32
  unsigned short* WrE = (unsigned short*)(wsf + 8732672);
  unsigned short* WrD = (unsigned short*)(wsf + 9027584);
  unsigned short* Ans = (unsigned short*)(wsf + 9322496);
  unsigned short* BmT = (unsigned short*)(wsf + 10371072);
  float* sraw = wsf + 11419648;                                 // 24,576
  float* vd   = wsf + 11444224;                                 // 8,192
  int*   smr  = (int*)(wsf + 11452416);                         // 8,192
  float* lacc = wsf + 11460608;
  unsigned* mm = (unsigned*)(wsf + 11460609);

  prep_k<<<2809, 256, 0, stream>>>(cf, w_enc, w_dec, fv, Xp, WrE, WrD, smr, vd,
                                   (float4*)sraw, lacc, mm);
  ansbmt_k<<<1184, 256, 0, stream>>>(fs, fd, smr, vd, Ans, BmT, Recp);
  encrec_k<<<384, 512, 0, stream>>>(Xp, WrE, b_enc, Midp, BmT, Ans, Recp);
  conv_dec_k<<<384, 512, 0, stream>>>(Midp, Recp, WrD, b_dec, cf, rec2, lacc, mm);
  score_conv_k<<<dim3(32, 3, 8), 256, 0, stream>>>(rec2, cf, w_val, mm, sraw);
  fuse_k<<<8192, 256, 0, stream>>>(cf, rec2, sraw, b_val, mm, lacc, out);
}